// Round 10
// baseline (633.958 us; speedup 1.0000x reference)
//
#include <hip/hip_runtime.h>
#include <hip/hip_bf16.h>
#include <stdint.h>

// DEQTrellisNetLM on MI355X (gfx950).
// B=4, L=1024, H=768, 4H=3072, NINP=512, K=2, NLAYER=10, NOUT=256.
//
// All GEMM operands FRAGMENT-TILE-MAJOR in global memory (16x32 MFMA tile =
// 1KB contiguous, MFMA lane order). Staging: gl_lds from tile+lane*16 (perfectly
// coalesced), LDS linear, ds_reads uniform+lane*16 (zero bank conflicts).
// GEMM: 256x256 tile, BK=64, 8 waves (2Mx4N), 8-phase schedule. RACE FIX (R9):
// counted vmcnt sits at the TAIL of even phases BEFORE the closing barrier, so
// every wave's wait precedes the barrier that publishes staged LDS; the next
// phase's ds_reads follow that barrier. Prologue: 12 loads, VM(8), barrier.
// Full iters: VM(8) at ph2/4/6/8. Last iter: VM(8)/VM(4)/VM(0)/none.
// Stage map (iter I): ph1:A(2I+1)ks1  ph2:B(2I+1)ks1  ph3:A(2I+2)ks0
//   ph4:B(2I+2)ks0  ph5:A(2I+2)ks1  ph6:B(2I+2)ks1  ph7:A(2I+3)ks0  ph8:B.
// h kept as two tiled copies (tap1 at t, tap0 at t+1); c time-major fp16;
// us4 fp16x4 gate-gathered; gate epilogue fused (gate = fn fragment index).

#define B_    4
#define L_    1024
#define LP1   1025
#define H_    768
#define NG_   3072
#define NINP_ 512
#define NOUT_ 256

typedef __bf16 bf16x8 __attribute__((ext_vector_type(8)));
typedef float f32x4 __attribute__((ext_vector_type(4)));
typedef _Float16 f16x4 __attribute__((ext_vector_type(4)));
using bf16_t = __hip_bfloat16;

__device__ __forceinline__ float sigf(float x){ return 1.f/(1.f + __expf(-x)); }
__device__ __forceinline__ float tanhf_(float x){
  float e = __expf(-2.f*fabsf(x));
  float r = (1.f - e)/(1.f + e);
  return x >= 0.f ? r : -r;
}

__device__ __forceinline__ void gl_lds16(const void* g, void* l){
  __builtin_amdgcn_global_load_lds(
    (const __attribute__((address_space(1))) uint32_t*)g,
    (__attribute__((address_space(3))) uint32_t*)l, 16, 0, 0);
}

// element index inside the H-tiled layout: [b][g=t>>4][kb=j>>5][512 elems]
__device__ __forceinline__ size_t htile_idx(int b, int t, int j){
  return ((size_t)((b*64 + (t>>4))*24) + (j>>5))*512
         + (size_t)((t&15)*8 + ((j>>3)&3)*128 + (j&7));
}

// ---- init ----
__global__ void init_k(const float* __restrict__ z0, bf16_t* __restrict__ XB,
                       bf16_t* __restrict__ HB0, bf16_t* __restrict__ HB1,
                       _Float16* __restrict__ C0, _Float16* __restrict__ C1){
  int tid = blockIdx.x*256 + threadIdx.x;
  if (tid < B_*NINP_){
    int b = tid >> 9, r = tid & 511;
    int kb = r>>5, lk = (r>>3)&3, e = r&7;
    XB[((size_t)(b*64*16) + kb)*512 + lk*128 + e] = __float2bfloat16(0.f);
  }
  if (tid < B_*H_){
    int b = tid / H_, j = tid % H_;
    bf16_t hz = __float2bfloat16(z0[b*2*H_ + j]);
    _Float16 cz = (_Float16)z0[b*2*H_ + H_ + j];
    size_t a = ((size_t)(b*64*24) + (j>>5))*512 + ((j>>3)&3)*128 + (j&7);
    HB0[a] = hz; HB1[a] = hz;
    size_t idx = (size_t)b*LP1*H_ + j;
    C0[idx] = cz; C1[idx] = cz;
  }
}

// ---- weight prep ----
__global__ void prep_w(const float* __restrict__ iw, const float* __restrict__ ib,
                       const float* __restrict__ cw, const float* __restrict__ cb,
                       bf16_t* __restrict__ WitT, bf16_t* __restrict__ WctT,
                       float* __restrict__ bias4){
  int op = blockIdx.x;
  int gate = (op >> 4) & 3;
  int j = ((op >> 6) << 4) | (op & 15);
  int o = gate*H_ + j;
  int nt = op >> 4, lrow = op & 15;
  const float2* s2 = (const float2*)(iw + (size_t)o*NINP_*2);
  for (int i = threadIdx.x; i < NINP_; i += 256){
    float2 v = s2[i];
    int k0 = i, k1 = NINP_ + i;
    WitT[((size_t)(nt*32 + (k0>>5)))*512 + lrow*8 + ((k0>>3)&3)*128 + (k0&7)] = __float2bfloat16(v.x);
    WitT[((size_t)(nt*32 + (k1>>5)))*512 + lrow*8 + ((k1>>3)&3)*128 + (k1&7)] = __float2bfloat16(v.y);
  }
  const float2* c2 = (const float2*)(cw + (size_t)o*H_*2);
  for (int i = threadIdx.x; i < H_; i += 256){
    float2 v = c2[i];
    int k0 = i, k1 = H_ + i;
    WctT[((size_t)(nt*48 + (k0>>5)))*512 + lrow*8 + ((k0>>3)&3)*128 + (k0&7)] = __float2bfloat16(v.x);
    WctT[((size_t)(nt*48 + (k1>>5)))*512 + lrow*8 + ((k1>>3)&3)*128 + (k1&7)] = __float2bfloat16(v.y);
  }
  if (threadIdx.x == 0) bias4[j*4 + gate] = ib[o] + cb[o];
}

// ---- X (B,512,1024) f32 -> XA (tap1, t) + XB (tap0, t+1) tiled bf16 ----
__global__ void tile_x(const float* __restrict__ X, bf16_t* __restrict__ XA,
                       bf16_t* __restrict__ XB){
  int b = blockIdx.z, i = blockIdx.y;
  int t = blockIdx.x*256 + threadIdx.x;
  bf16_t bv = __float2bfloat16(X[((size_t)b*NINP_ + i)*L_ + t]);
  int kb = i>>5, lk = (i>>3)&3, e = i&7;
  XA[((size_t)((b*64 + (t>>4))*16) + kb)*512 + (t&15)*8 + lk*128 + e] = bv;
  if (t < L_-1){
    int t1 = t + 1;
    XB[((size_t)((b*64 + (t1>>4))*16) + kb)*512 + (t1&15)*8 + lk*128 + e] = bv;
  }
}

// ---- 256^2 8-wave 8-phase GEMM ----
// MODE 0: us4 = gather(A*Bt + bias); fused first gate step (h=0) -> HA/HB/C
// MODE 1: gates(A*Bt + us4) -> HA/HB/C
// MODE 2: gates(A*Bt + us4) -> outF (B,L,NOUT) f32 directly
template<int KTOT, int MODE>
__launch_bounds__(512, 2)
__global__ void gemm8(const bf16_t* __restrict__ A1, const bf16_t* __restrict__ A0,
                      const bf16_t* __restrict__ Bt, const float* __restrict__ bias4,
                      f16x4* __restrict__ us4, const _Float16* __restrict__ Cprev,
                      _Float16* __restrict__ Cnew, bf16_t* __restrict__ HAn,
                      bf16_t* __restrict__ HBn, float* __restrict__ outF, int bn_base){
  extern __shared__ __align__(1024) char smem[];   // 128 KB
  char* ldsA = smem;            // [dbuf][ks][tile 0..15][1KB]
  char* ldsB = smem + 65536;

  const int tid = threadIdx.x;
  const int l  = tid & 63;
  const int w  = tid >> 6;            // 0..7
  const int wm = w >> 2, wn = w & 3;  // 2M x 4N
  const int lr = l & 15, lk = l >> 4;

  const int nwg = gridDim.x * gridDim.y;
  int flat = blockIdx.y * gridDim.x + blockIdx.x;
  flat = (flat & 7) * (nwg >> 3) + (flat >> 3);
  const int bm0 = (flat & 15) * 256;            // gridDim.x == 16
  const int bn0 = bn_base + (flat >> 4) * 256;

  constexpr int NT64 = KTOT / 64;
  constexpr int NI   = NT64 / 2;
  constexpr int KB0  = (KTOT == 1024) ? 16 : 24;  // 32-tiles per tap
  constexpr int KBB  = KTOT / 32;

  f32x4 acc[8][4];
#pragma unroll
  for (int i = 0; i < 8; ++i)
#pragma unroll
    for (int jj = 0; jj < 4; ++jj)
      acc[i][jj] = (f32x4){0.f,0.f,0.f,0.f};

  // staging sources: wave w stages fragment tiles n*8+w (n=0,1)
  const int bI = bm0 >> 10;
  const int g0 = (bm0 >> 4) & 63;
  const char* sA0[2]; const char* sA1[2]; const char* sB[2];
#pragma unroll
  for (int n = 0; n < 2; ++n){
    const int g = g0 + n*8 + w;
    sA0[n] = (const char*)A0 + (((size_t)(bI*64 + g)*KB0) << 10) + l*16;
    sA1[n] = (const char*)A1 + (((size_t)(bI*64 + g)*KB0) << 10) + l*16;
    const int nt = (bn0 >> 4) + n*8 + w;
    sB[n]  = (const char*)Bt + (((size_t)nt*KBB) << 10) + l*16;
  }

#define SA(T, KS, DB) if ((T) < NT64) { \
    const int kb_ = (T)*2 + (KS); \
    char* d_ = ldsA + (DB)*32768 + (KS)*16384 + w*1024; \
    if (kb_ < KB0) { \
      gl_lds16(sA0[0] + ((size_t)kb_ << 10), d_); \
      gl_lds16(sA0[1] + ((size_t)kb_ << 10), d_ + 8192); \
    } else { \
      gl_lds16(sA1[0] + ((size_t)(kb_ - KB0) << 10), d_); \
      gl_lds16(sA1[1] + ((size_t)(kb_ - KB0) << 10), d_ + 8192); \
    } }
#define SB(T, KS, DB) if ((T) < NT64) { \
    const int kb_ = (T)*2 + (KS); \
    char* d_ = ldsB + (DB)*32768 + (KS)*16384 + w*1024; \
    gl_lds16(sB[0] + ((size_t)kb_ << 10), d_); \
    gl_lds16(sB[1] + ((size_t)kb_ << 10), d_ + 8192); }

  bf16x8 af[4], bv[4];
#define RD_B(DB, KS) { \
    const char* bb_ = ldsB + (DB)*32768 + (KS)*16384 + (wn*4)*1024 + l*16; \
    bv[0] = *(const bf16x8*)(bb_); \
    bv[1] = *(const bf16x8*)(bb_ + 1024); \
    bv[2] = *(const bf16x8*)(bb_ + 2048); \
    bv[3] = *(const bf16x8*)(bb_ + 3072); }
#define RD_A(DB, MH, KS) { \
    const char* ab_ = ldsA + (DB)*32768 + (KS)*16384 + (wm*8 + (MH)*4)*1024 + l*16; \
    af[0] = *(const bf16x8*)(ab_); \
    af[1] = *(const bf16x8*)(ab_ + 1024); \
    af[2] = *(const bf16x8*)(ab_ + 2048); \
    af[3] = *(const bf16x8*)(ab_ + 3072); }

#define VM8 asm volatile("s_waitcnt vmcnt(8)" ::: "memory");
#define VM4 asm volatile("s_waitcnt vmcnt(4)" ::: "memory");
#define VM0 asm volatile("s_waitcnt vmcnt(0)" ::: "memory");
#define VMN

// MM(MH, W): pre-barrier, MFMA cluster, then per-wave counted wait W BEFORE the
// closing barrier (publishes staged LDS to all waves for the next phase's reads).
#define MM(MH, W) \
    __builtin_amdgcn_s_barrier(); \
    __builtin_amdgcn_sched_barrier(0); \
    __builtin_amdgcn_s_setprio(1); \
    _Pragma("unroll") for (int fm = 0; fm < 4; ++fm) \
      _Pragma("unroll") for (int fn = 0; fn < 4; ++fn) \
        acc[(MH)*4 + fm][fn] = __builtin_amdgcn_mfma_f32_16x16x32_bf16(af[fm], bv[fn], acc[(MH)*4 + fm][fn], 0, 0, 0); \
    __builtin_amdgcn_s_setprio(0); \
    W \
    __builtin_amdgcn_s_barrier(); \
    __builtin_amdgcn_sched_barrier(0);

#define ITER(I, W4, W6, W8) \
    RD_A(0,0,0) RD_B(0,0) SA(2*(I)+1, 1, 1) MM(0, VMN)   /* ph1 */ \
    RD_A(0,1,0)           SB(2*(I)+1, 1, 1) MM(1, VM8)   /* ph2 */ \
    RD_A(0,0,1) RD_B(0,1) SA(2*(I)+2, 0, 0) MM(0, VMN)   /* ph3 */ \
    RD_A(0,1,1)           SB(2*(I)+2, 0, 0) MM(1, W4)    /* ph4 */ \
    RD_A(1,0,0) RD_B(1,0) SA(2*(I)+2, 1, 0) MM(0, VMN)   /* ph5 */ \
    RD_A(1,1,0)           SB(2*(I)+2, 1, 0) MM(1, W6)    /* ph6 */ \
    RD_A(1,0,1) RD_B(1,1) SA(2*(I)+3, 0, 1) MM(0, VMN)   /* ph7 */ \
    RD_A(1,1,1)           SB(2*(I)+3, 0, 1) MM(1, W8)    /* ph8 */

  // prologue: T0 both halves + T1 ks0 (12 loads); publish T0ks0 to all waves
  SA(0,0,0) SB(0,0,0) SA(0,1,0) SB(0,1,0) SA(1,0,1) SB(1,0,1)
  VM8
  __builtin_amdgcn_s_barrier();
  __builtin_amdgcn_sched_barrier(0);

  for (int i = 0; i < NI-1; ++i){ ITER(i, VM8, VM8, VM8) }
  { ITER(NI-1, VM4, VM0, VMN) }

#undef SA
#undef SB
#undef RD_A
#undef RD_B
#undef VM8
#undef VM4
#undef VM0
#undef VMN
#undef MM
#undef ITER

  // ---- fused gate epilogue ----
  const int jblk = (bn0 >> 6) + wn;
  const int j = jblk*16 + lr;

  if (MODE == 0){
    const float4 bz = ((const float4*)bias4)[j];
#pragma unroll
    for (int mf = 0; mf < 8; ++mf){
      const int mbase = bm0 + wm*128 + mf*16 + lk*4;
#pragma unroll
      for (int r = 0; r < 4; ++r){
        const int m = mbase + r;
        const int b = m >> 10, t = m & 1023;
        const float ig = acc[mf][0][r] + bz.x;
        const float og = acc[mf][1][r] + bz.y;
        const float gg = acc[mf][2][r] + bz.z;
        const float fg = acc[mf][3][r] + bz.w;
        us4[(size_t)m*H_ + j] = (f16x4){ (_Float16)ig, (_Float16)og,
                                         (_Float16)gg, (_Float16)fg };
        const float cp = (t == 0) ? (float)Cprev[(size_t)b*LP1*H_ + j] : 0.f;
        const float c  = sigf(fg)*cp + sigf(ig)*tanhf_(gg);
        const float h  = sigf(og)*tanhf_(c);
        Cnew[(size_t)(b*LP1 + t + 1)*H_ + j] = (_Float16)c;
        bf16_t hb = __float2bfloat16(h);
        HAn[htile_idx(b, t, j)] = hb;
        if (t < L_-1) HBn[htile_idx(b, t+1, j)] = hb;
      }
    }
  } else {
#pragma unroll
    for (int mf = 0; mf < 8; ++mf){
      const int mbase = bm0 + wm*128 + mf*16 + lk*4;
      f16x4 uv[4]; _Float16 cp16[4];
#pragma unroll
      for (int r = 0; r < 4; ++r){
        const int m = mbase + r;
        const int b = m >> 10, t = m & 1023;
        uv[r]   = us4[(size_t)m*H_ + j];
        cp16[r] = Cprev[(size_t)(b*LP1 + t)*H_ + j];
      }
#pragma unroll
      for (int r = 0; r < 4; ++r){
        const int m = mbase + r;
        const int b = m >> 10, t = m & 1023;
        const float ig = acc[mf][0][r] + (float)uv[r][0];
        const float og = acc[mf][1][r] + (float)uv[r][1];
        const float gg = acc[mf][2][r] + (float)uv[r][2];
        const float fg = acc[mf][3][r] + (float)uv[r][3];
        const float c  = sigf(fg)*(float)cp16[r] + sigf(ig)*tanhf_(gg);
        const float h  = sigf(og)*tanhf_(c);
        if (MODE == 1){
          Cnew[(size_t)(b*LP1 + t + 1)*H_ + j] = (_Float16)c;
          bf16_t hb = __float2bfloat16(h);
          HAn[htile_idx(b, t, j)] = hb;
          if (t < L_-1) HBn[htile_idx(b, t+1, j)] = hb;
        } else {
          outF[(size_t)(b*1024 + t)*NOUT_ + (j - (H_ - NOUT_))] = h;
        }
      }
    }
  }
}

// ---- tail: full-channel state at t=L for z0_out, K-split 4-way ----
__global__ void tail_k(const bf16_t* __restrict__ HA9, const bf16_t* __restrict__ HB9,
                       const _Float16* __restrict__ C9, const f16x4* __restrict__ us4,
                       const bf16_t* __restrict__ WctT, float* __restrict__ out){
  __shared__ float red[4][64];
  const int b = blockIdx.y;
  const int ob = blockIdx.x;
  const int opl = threadIdx.x & 63;
  const int q   = threadIdx.x >> 6;
  const int nt = ob*4 + (opl >> 4);
  const int lr = opl & 15;

  const bf16_t* hsrcb = (q < 2) ? HB9 : HA9;
  const int j0q = (q < 2) ? q*384 : (q-2)*384;
  const size_t gbase = (size_t)(b*64 + 63) * 24;
  const bf16_t* wbase = WctT + ((size_t)(nt*48 + ((q*384)>>5)))*512 + lr*8;

  float s = 0.f;
#pragma unroll 4
  for (int i = 0; i < 48; ++i){
    const int koff = i*8;
    const int j = j0q + koff;
    bf16x8 wv = *reinterpret_cast<const bf16x8*>(wbase + (koff>>5)*512 + ((koff>>3)&3)*128);
    bf16x8 hv = *reinterpret_cast<const bf16x8*>(hsrcb + (gbase + (j>>5))*512 + 120 + ((j>>3)&3)*128);
#pragma unroll
    for (int u = 0; u < 8; ++u) s += (float)hv[u]*(float)wv[u];
  }
  red[q][opl] = s;
  __syncthreads();
  if (threadIdx.x < 64){
    const int gate = (opl >> 4) & 3;
    const int j = ob*16 + lr;
    float sv = red[0][opl] + red[1][opl] + red[2][opl] + red[3][opl];
    sv += (float)us4[(size_t)(b*1024 + 1023)*H_ + j][gate];
    const float si = __shfl(sv, lr);
    const float so = __shfl(sv, lr + 16);
    const float sg = __shfl(sv, lr + 32);
    const float sf = __shfl(sv, lr + 48);
    if (gate == 0){
      const float cp = (float)C9[(size_t)(b*LP1 + 1023)*H_ + j];
      const float c = sigf(sf)*cp + sigf(si)*tanhf_(sg);
      const float h = sigf(so)*tanhf_(c);
      out[B_*L_*NOUT_ + b*2*H_ + j]      = h;
      out[B_*L_*NOUT_ + b*2*H_ + H_ + j] = c;
    }
  }
}

extern "C" void kernel_launch(void* const* d_in, const int* in_sizes, int n_in,
                              void* d_out, int out_size, void* d_ws, size_t ws_size,
                              hipStream_t stream){
  const float* X   = (const float*)d_in[0];
  const float* z0  = (const float*)d_in[1];
  const float* iw  = (const float*)d_in[2];
  const float* ib  = (const float*)d_in[3];
  const float* cw  = (const float*)d_in[4];
  const float* cbv = (const float*)d_in[5];
  float* out = (float*)d_out;

  char* ws = (char*)d_ws;
  f16x4*    us4  = (f16x4*)   (ws + 0);           // 25165824
  bf16_t*   XA   = (bf16_t*)  (ws + 25165824);    // 4194304
  bf16_t*   XB   = (bf16_t*)  (ws + 29360128);    // 4194304
  bf16_t*   WitT = (bf16_t*)  (ws + 33554432);    // 6291456
  bf16_t*   WctT = (bf16_t*)  (ws + 39845888);    // 9437184
  float*    bias4= (float*)   (ws + 49283072);    // 12288
  bf16_t*   HA0  = (bf16_t*)  (ws + 49295360);    // 6291456
  bf16_t*   HB0  = (bf16_t*)  (ws + 55586816);
  bf16_t*   HA1  = (bf16_t*)  (ws + 61878272);
  bf16_t*   HB1  = (bf16_t*)  (ws + 68169728);
  _Float16* C0   = (_Float16*)(ws + 74461184);    // 6297600
  _Float16* C1   = (_Float16*)(ws + 80758784);    // end 87056384

  hipFuncSetAttribute((const void*)gemm8<1024,0>,
                      hipFuncAttributeMaxDynamicSharedMemorySize, 131072);
  hipFuncSetAttribute((const void*)gemm8<1536,1>,
                      hipFuncAttributeMaxDynamicSharedMemorySize, 131072);
  hipFuncSetAttribute((const void*)gemm8<1536,2>,
                      hipFuncAttributeMaxDynamicSharedMemorySize, 131072);

  init_k<<<12, 256, 0, stream>>>(z0, XB, HB0, HB1, C0, C1);
  prep_w<<<NG_, 256, 0, stream>>>(iw, ib, cw, cbv, WitT, WctT, bias4);
  tile_x<<<dim3(4, NINP_, B_), 256, 0, stream>>>(X, XA, XB);

  // inject GEMM (K=1024) -> us4, fused first gate step -> S1
  gemm8<1024, 0><<<dim3(16, 12), 512, 131072, stream>>>(
      XA, XB, WitT, bias4, us4, C0, C0, HA0, HB0, nullptr, 0);

  // iterations 2..9: fused GEMM (K=1536) + gates, double-buffered -> S9
  bf16_t* HAp = HA0; bf16_t* HBp = HB0; _Float16* Cp = C0;
  bf16_t* HAn = HA1; bf16_t* HBn = HB1; _Float16* Cn = C1;
  for (int it = 1; it <= 8; ++it){
    gemm8<1536, 1><<<dim3(16, 12), 512, 131072, stream>>>(
        HAp, HBp, WctT, nullptr, us4, Cp, Cn, HAn, HBn, nullptr, 0);
    bf16_t* ta = HAp; HAp = HAn; HAn = ta;
    bf16_t* tb = HBp; HBp = HBn; HBn = tb;
    _Float16* tc = Cp; Cp = Cn; Cn = tc;
  }

  // z0_out: step 10 at t=1023, full channels, from S9
  tail_k<<<dim3(48, B_), 256, 0, stream>>>(HAp, HBp, Cp, us4, WctT, out);

  // step 10 (reduced N): j in [512,768) -> writes out[] directly
  gemm8<1536, 2><<<dim3(16, 4), 512, 131072, stream>>>(
      HAp, HBp, WctT, nullptr, us4, Cp, nullptr, nullptr, nullptr, out, 2048);
}